// Round 1
// baseline (135.201 us; speedup 1.0000x reference)
//
#include <hip/hip_runtime.h>

#define NSIDE 256
#define KIN   1024   // NPATCH * HDIM
#define HD    64

// ---------------------------------------------------------------------------
// K1: per (b,c) block. Stream y = x + pos_enc once; build
//   colsum[pr][col] = sum over rows with row%16==pr of y[row][col]
//   rowsum[row][pc] = sum over cols with col%16==pc of y[row][col]
// then project with Wv/Wh to vcomp/hcomp (1024 each), incl. 16x bias.
// 1024 threads: wave w owns rows == w (mod 16); lane l owns cols 4l..4l+3.
// ---------------------------------------------------------------------------
__global__ __launch_bounds__(1024) void k1_reduce(
    const float* __restrict__ x, const float* __restrict__ pe,
    const float* __restrict__ Wv, const float* __restrict__ bv,
    const float* __restrict__ Wh, const float* __restrict__ bh,
    float* __restrict__ vcomp, float* __restrict__ hcomp)
{
    __shared__ float colsum[16][256];   // [pr][col]
    __shared__ float rowsum[256][16];   // [row][pc]

    const int bc = blockIdx.x;          // b*16 + c
    const int c  = bc & 15;
    const int t  = threadIdx.x;
    const int w  = t >> 6;              // wave 0..15
    const int l  = t & 63;              // lane

    const float* xb  = x  + (size_t)bc * (NSIDE * NSIDE);
    const float* peb = pe + (size_t)c  * (NSIDE * NSIDE);

    float4 cacc = make_float4(0.f, 0.f, 0.f, 0.f);

    #pragma unroll 4
    for (int base = 0; base < 256; base += 16) {
        const int row = base + w;       // row % 16 == w
        float4 xv = *(const float4*)(xb  + row * 256 + 4 * l);
        float4 pv = *(const float4*)(peb + row * 256 + 4 * l);
        float4 y;
        y.x = xv.x + pv.x; y.y = xv.y + pv.y;
        y.z = xv.z + pv.z; y.w = xv.w + pv.w;

        cacc.x += y.x; cacc.y += y.y; cacc.z += y.z; cacc.w += y.w;

        // rowsum reduce across lanes with same (l % 4): butterfly 4,8,16,32
        float4 s = y;
        #pragma unroll
        for (int m = 4; m <= 32; m <<= 1) {
            s.x += __shfl_xor(s.x, m);
            s.y += __shfl_xor(s.y, m);
            s.z += __shfl_xor(s.z, m);
            s.w += __shfl_xor(s.w, m);
        }
        if (l < 4) {
            rowsum[row][4 * l + 0] = s.x;
            rowsum[row][4 * l + 1] = s.y;
            rowsum[row][4 * l + 2] = s.z;
            rowsum[row][4 * l + 3] = s.w;
        }
    }
    colsum[w][4 * l + 0] = cacc.x;
    colsum[w][4 * l + 1] = cacc.y;
    colsum[w][4 * l + 2] = cacc.z;
    colsum[w][4 * l + 3] = cacc.w;
    __syncthreads();

    // Phase B: thread (seg=w, d=l) computes
    //   vcomp[seg*64+d] = sum_{k=pr*16+pc} colsum[pr][seg*16+pc] * Wv[d][k] + 16*bv[d]
    //   hcomp[seg*64+d] = sum_{k} rowsum[seg*16+pr][pc] * Wh[d][k] + 16*bh[d]
    const int d = l, seg = w;
    float accV = 0.f, accH = 0.f;
    #pragma unroll 4
    for (int k = 0; k < 256; k += 4) {
        const int pr = k >> 4, pc = k & 15;
        float4 wv = *(const float4*)(Wv + d * 256 + k);
        float4 wh = *(const float4*)(Wh + d * 256 + k);
        float4 cs = *(const float4*)&colsum[pr][seg * 16 + pc];   // wave-uniform
        float4 rs = *(const float4*)&rowsum[seg * 16 + pr][pc];   // wave-uniform
        accV += wv.x * cs.x + wv.y * cs.y + wv.z * cs.z + wv.w * cs.w;
        accH += wh.x * rs.x + wh.y * rs.y + wh.z * rs.z + wh.w * rs.w;
    }
    vcomp[bc * KIN + seg * HD + d] = accV + 16.f * bv[d];
    hcomp[bc * KIN + seg * HD + d] = accH + 16.f * bh[d];
}

// ---------------------------------------------------------------------------
// K2: V[bc][r][n] = sum_k vcomp[bc][k]*Vw[r][n][k] + Vb[r][n]   (H likewise)
// GEMM tiling: block = 16 bc x 16 n (x3 r, x2 matrices), K-chunks of 128.
// Grid (16 n-tiles, 16 bc-tiles) so Vw/Hw (6 MB) is read 16x, not 256x.
// ---------------------------------------------------------------------------
__global__ __launch_bounds__(256) void k2_proj(
    const float* __restrict__ vcomp, const float* __restrict__ hcomp,
    const float* __restrict__ Vw, const float* __restrict__ Vb,
    const float* __restrict__ Hw, const float* __restrict__ Hb,
    float* __restrict__ Vo, float* __restrict__ Ho)
{
    __shared__ float sav[16][132];   // vcomp tile [bcl][k] (+4 pad)
    __shared__ float sah[16][132];
    __shared__ float sbv[48][132];   // Vw tile [r*16+nl][k]
    __shared__ float sbh[48][132];

    const int n0  = blockIdx.x * 16;
    const int bc0 = blockIdx.y * 16;
    const int t   = threadIdx.x;
    const int bcl = t >> 4;          // 0..15
    const int nl  = t & 15;          // 0..15

    float accV[3] = {0.f, 0.f, 0.f};
    float accH[3] = {0.f, 0.f, 0.f};

    for (int k0 = 0; k0 < KIN; k0 += 128) {
        #pragma unroll
        for (int j = 0; j < 8; j++) {            // A tiles: 16x128 each
            int idx = t + j * 256;
            int rr = idx >> 7, kk = idx & 127;
            sav[rr][kk] = vcomp[(size_t)(bc0 + rr) * KIN + k0 + kk];
            sah[rr][kk] = hcomp[(size_t)(bc0 + rr) * KIN + k0 + kk];
        }
        #pragma unroll
        for (int j = 0; j < 24; j++) {           // B tiles: 48x128 each
            int idx = t + j * 256;
            int rr = idx >> 7, kk = idx & 127;
            int r = rr >> 4, nn = rr & 15;
            sbv[rr][kk] = Vw[((size_t)r * 256 + n0 + nn) * KIN + k0 + kk];
            sbh[rr][kk] = Hw[((size_t)r * 256 + n0 + nn) * KIN + k0 + kk];
        }
        __syncthreads();

        #pragma unroll 8
        for (int kk = 0; kk < 128; kk += 4) {
            float4 av = *(const float4*)&sav[bcl][kk];
            float4 ah = *(const float4*)&sah[bcl][kk];
            #pragma unroll
            for (int r = 0; r < 3; r++) {
                float4 b4 = *(const float4*)&sbv[r * 16 + nl][kk];
                accV[r] += av.x * b4.x + av.y * b4.y + av.z * b4.z + av.w * b4.w;
                float4 c4 = *(const float4*)&sbh[r * 16 + nl][kk];
                accH[r] += ah.x * c4.x + ah.y * c4.y + ah.z * c4.z + ah.w * c4.w;
            }
        }
        __syncthreads();
    }

    #pragma unroll
    for (int r = 0; r < 3; r++) {
        Vo[((size_t)(bc0 + bcl) * 3 + r) * 256 + n0 + nl] = accV[r] + Vb[r * 256 + n0 + nl];
        Ho[((size_t)(bc0 + bcl) * 3 + r) * 256 + n0 + nl] = accH[r] + Hb[r * 256 + n0 + nl];
    }
}

// ---------------------------------------------------------------------------
// K3: out[bc][n][m] = sum_r V[bc][r][n] * H[bc][r][m].  Write-bound (67 MB).
// Block: one bc x 32-row n-tile; thread t = m. Coalesced stores.
// ---------------------------------------------------------------------------
__global__ __launch_bounds__(256) void k3_outer(
    const float* __restrict__ Vo, const float* __restrict__ Ho,
    float* __restrict__ out)
{
    const int bc = blockIdx.y;
    const int nt = blockIdx.x;       // 0..7
    const int t  = threadIdx.x;      // m

    const float h0 = Ho[((size_t)bc * 3 + 0) * 256 + t];
    const float h1 = Ho[((size_t)bc * 3 + 1) * 256 + t];
    const float h2 = Ho[((size_t)bc * 3 + 2) * 256 + t];

    __shared__ float sv[3][32];
    if (t < 96) {
        int r = t / 32, nn = t % 32;
        sv[r][nn] = Vo[((size_t)bc * 3 + r) * 256 + nt * 32 + nn];
    }
    __syncthreads();

    float* ob = out + ((size_t)bc * 256 + nt * 32) * 256;
    #pragma unroll 4
    for (int nn = 0; nn < 32; nn++) {
        float v = sv[0][nn] * h0 + sv[1][nn] * h1 + sv[2][nn] * h2;
        ob[nn * 256 + t] = v;
    }
}

extern "C" void kernel_launch(void* const* d_in, const int* in_sizes, int n_in,
                              void* d_out, int out_size, void* d_ws, size_t ws_size,
                              hipStream_t stream)
{
    const float* x  = (const float*)d_in[0];
    const float* pe = (const float*)d_in[1];
    const float* Wv = (const float*)d_in[2];
    const float* bv = (const float*)d_in[3];
    const float* Wh = (const float*)d_in[4];
    const float* bh = (const float*)d_in[5];
    const float* Vw = (const float*)d_in[6];
    const float* Vb = (const float*)d_in[7];
    const float* Hw = (const float*)d_in[8];
    const float* Hb = (const float*)d_in[9];
    float* out = (float*)d_out;

    float* vcomp = (float*)d_ws;               // 256*1024 f32 = 1 MB
    float* hcomp = vcomp + 256 * KIN;          // 1 MB
    float* Vo    = hcomp + 256 * KIN;          // 256*3*256 f32 = 768 KB
    float* Ho    = Vo + 256 * 3 * 256;         // 768 KB

    k1_reduce<<<256, 1024, 0, stream>>>(x, pe, Wv, bv, Wh, bh, vcomp, hcomp);
    k2_proj<<<dim3(16, 16), 256, 0, stream>>>(vcomp, hcomp, Vw, Vb, Hw, Hb, Vo, Ho);
    k3_outer<<<dim3(8, 256), 256, 0, stream>>>(Vo, Ho, out);
}

// Round 3
// 94.033 us; speedup vs baseline: 1.4378x; 1.4378x over previous
//
#include <hip/hip_runtime.h>

#define KIN 1024

// ---------------------------------------------------------------------------
// K0: (a) repack W (64d x 256k) -> Wq[kq][d] float4 so phase-B reads coalesce;
//     (b) per-channel pos_enc partial sums:
//         pecol[c][pr][col] = sum_{rows==pr mod 16} pe[c][row][col]
//         perow[c][row][pc] = sum_{cols==pc mod 16} pe[c][row][col]
// grid 16 (c), 1024 threads.
// ---------------------------------------------------------------------------
__global__ __launch_bounds__(1024) void k0_prep(
    const float* __restrict__ Wv, const float* __restrict__ Wh,
    const float* __restrict__ pe,
    float4* __restrict__ Wqv, float4* __restrict__ Wqh,
    float* __restrict__ pecol, float* __restrict__ perow)
{
    const int c = blockIdx.x;
    const int t = threadIdx.x;

    if (t < 256) {                       // repack share: 256 float4 per block
        int idx = c * 256 + t;           // 0..4095
        int kq = idx >> 6, d = idx & 63;
        Wqv[idx] = *(const float4*)(Wv + d * 256 + 4 * kq);
        Wqh[idx] = *(const float4*)(Wh + d * 256 + 4 * kq);
    }

    const int w = t >> 6, l = t & 63;
    const float* peb = pe + (size_t)c * 65536;
    float4 cacc = make_float4(0.f, 0.f, 0.f, 0.f);

    #pragma unroll 4
    for (int j = 0; j < 16; ++j) {
        const int row = j * 16 + w;
        float4 y = *(const float4*)(peb + row * 256 + 4 * l);
        cacc.x += y.x; cacc.y += y.y; cacc.z += y.z; cacc.w += y.w;
        float4 s = y;
        #pragma unroll
        for (int m = 4; m <= 32; m <<= 1) {
            s.x += __shfl_xor(s.x, m);
            s.y += __shfl_xor(s.y, m);
            s.z += __shfl_xor(s.z, m);
            s.w += __shfl_xor(s.w, m);
        }
        if (l < 4)
            *(float4*)(perow + ((size_t)c * 256 + row) * 16 + 4 * l) = s;
    }
    *(float4*)(pecol + ((size_t)c * 16 + w) * 256 + 4 * l) = cacc;
}

// ---------------------------------------------------------------------------
// K1: per (b,c). Phase A streams ONLY x (16 independent float4 loads/wave),
// adds pe partials at store time. Phase B: coalesced Wq outer-product.
// 1024 threads: wave w owns rows == w (mod 16); 16 waves split V/H in phase B.
// ---------------------------------------------------------------------------
__global__ __launch_bounds__(1024) void k1_reduce(
    const float* __restrict__ x,
    const float4* __restrict__ Wqv, const float* __restrict__ bv,
    const float4* __restrict__ Wqh, const float* __restrict__ bh,
    const float* __restrict__ pecol, const float* __restrict__ perow,
    float* __restrict__ vcomp, float* __restrict__ hcomp)
{
    __shared__ float colsum[16][256];
    __shared__ float rowsum[256][16];

    const int bc = blockIdx.x, c = bc & 15, t = threadIdx.x;
    const int w = t >> 6, l = t & 63;
    const float* xb = x + (size_t)bc * 65536;

    float4 y[16];
    #pragma unroll
    for (int j = 0; j < 16; ++j)
        y[j] = *(const float4*)(xb + (j * 16 + w) * 256 + 4 * l);

    float4 cacc = make_float4(0.f, 0.f, 0.f, 0.f);
    #pragma unroll
    for (int j = 0; j < 16; ++j) {
        cacc.x += y[j].x; cacc.y += y[j].y; cacc.z += y[j].z; cacc.w += y[j].w;
        float4 s = y[j];
        #pragma unroll
        for (int m = 4; m <= 32; m <<= 1) {
            s.x += __shfl_xor(s.x, m);
            s.y += __shfl_xor(s.y, m);
            s.z += __shfl_xor(s.z, m);
            s.w += __shfl_xor(s.w, m);
        }
        if (l < 4) {
            const int row = j * 16 + w;
            float4 p = *(const float4*)(perow + ((size_t)c * 256 + row) * 16 + 4 * l);
            s.x += p.x; s.y += p.y; s.z += p.z; s.w += p.w;
            *(float4*)&rowsum[row][4 * l] = s;
        }
    }
    {
        float4 p = *(const float4*)(pecol + ((size_t)c * 16 + w) * 256 + 4 * l);
        cacc.x += p.x; cacc.y += p.y; cacc.z += p.z; cacc.w += p.w;
        *(float4*)&colsum[w][4 * l] = cacc;
    }
    __syncthreads();

    // Phase B: wave w<8 -> V segs {2w,2w+1}; w>=8 -> H segs {2(w-8),2(w-8)+1}
    const int ws2 = (w & 7) * 2;
    float a0 = 0.f, a1 = 0.f;
    if (w < 8) {
        #pragma unroll 4
        for (int kq = 0; kq < 64; ++kq) {
            float4 wq = Wqv[kq * 64 + l];            // coalesced 1KB
            const int pr = kq >> 2, pc4 = (kq & 3) * 4;
            float4 c0 = *(const float4*)&colsum[pr][(ws2 + 0) * 16 + pc4];
            float4 c1 = *(const float4*)&colsum[pr][(ws2 + 1) * 16 + pc4];
            a0 += wq.x*c0.x + wq.y*c0.y + wq.z*c0.z + wq.w*c0.w;
            a1 += wq.x*c1.x + wq.y*c1.y + wq.z*c1.z + wq.w*c1.w;
        }
        const float b = 16.f * bv[l];
        float* o = vcomp + (size_t)bc * KIN + ws2 * 64 + l;
        o[0] = a0 + b; o[64] = a1 + b;
    } else {
        #pragma unroll 4
        for (int kq = 0; kq < 64; ++kq) {
            float4 wq = Wqh[kq * 64 + l];
            const int pr = kq >> 2, pc4 = (kq & 3) * 4;
            float4 r0 = *(const float4*)&rowsum[(ws2 + 0) * 16 + pr][pc4];
            float4 r1 = *(const float4*)&rowsum[(ws2 + 1) * 16 + pr][pc4];
            a0 += wq.x*r0.x + wq.y*r0.y + wq.z*r0.z + wq.w*r0.w;
            a1 += wq.x*r1.x + wq.y*r1.y + wq.z*r1.z + wq.w*r1.w;
        }
        const float b = 16.f * bh[l];
        float* o = hcomp + (size_t)bc * KIN + ws2 * 64 + l;
        o[0] = a0 + b; o[64] = a1 + b;
    }
}

// ---------------------------------------------------------------------------
// K2: P[ks][bc][r][n] = sum_{k in ks-chunk} A[bc][k] * B[r][n][k]
// Tile 64bc x 64n x 3r, micro 4x3x4. grid (4 n-tiles, 4 bc-tiles * KS, 2).
// ---------------------------------------------------------------------------
__global__ __launch_bounds__(256) void k2_proj(
    const float* __restrict__ vcomp, const float* __restrict__ hcomp,
    const float* __restrict__ Vw, const float* __restrict__ Hw,
    float* __restrict__ Vp, float* __restrict__ Hp, int KSplit, int KC)
{
    __shared__ float sA[32][68];    // [k][bc]
    __shared__ float sB[32][196];   // [k][r*64+n]

    const int mat = blockIdx.z;
    const float* A = mat ? hcomp : vcomp;
    const float* B = mat ? Hw : Vw;
    float*       P = mat ? Hp : Vp;

    const int n0  = blockIdx.x * 64;
    const int bct = blockIdx.y / KSplit, ks = blockIdx.y % KSplit;
    const int bc0 = bct * 64;
    const int t   = threadIdx.x, tb = t >> 4, tn = t & 15;

    float acc[4][3][4];
    #pragma unroll
    for (int i = 0; i < 4; ++i)
        #pragma unroll
        for (int r = 0; r < 3; ++r)
            #pragma unroll
            for (int j = 0; j < 4; ++j) acc[i][r][j] = 0.f;

    const int nch = KC >> 5;
    for (int ch = 0; ch < nch; ++ch) {
        const int k0 = ks * KC + ch * 32;
        #pragma unroll
        for (int s = 0; s < 2; ++s) {               // A: 64x32
            int q = t + s * 256;
            int bcl = q >> 3, kq = q & 7;
            float4 v = *(const float4*)(A + (size_t)(bc0 + bcl) * KIN + k0 + 4 * kq);
            sA[4*kq+0][bcl] = v.x; sA[4*kq+1][bcl] = v.y;
            sA[4*kq+2][bcl] = v.z; sA[4*kq+3][bcl] = v.w;
        }
        #pragma unroll
        for (int s = 0; s < 6; ++s) {               // B: 192x32
            int q = t + s * 256;
            int rr = q >> 3, kq = q & 7;
            int r = rr >> 6, nn = rr & 63;
            float4 v = *(const float4*)(B + ((size_t)(r * 256 + n0 + nn)) * KIN + k0 + 4 * kq);
            sB[4*kq+0][rr] = v.x; sB[4*kq+1][rr] = v.y;
            sB[4*kq+2][rr] = v.z; sB[4*kq+3][rr] = v.w;
        }
        __syncthreads();

        #pragma unroll 8
        for (int kk = 0; kk < 32; ++kk) {
            float4 av = *(const float4*)&sA[kk][4 * tb];
            float4 b0 = *(const float4*)&sB[kk][0 * 64 + 4 * tn];
            float4 b1 = *(const float4*)&sB[kk][1 * 64 + 4 * tn];
            float4 b2 = *(const float4*)&sB[kk][2 * 64 + 4 * tn];
            float a_[4] = {av.x, av.y, av.z, av.w};
            float b_[3][4] = {{b0.x,b0.y,b0.z,b0.w},{b1.x,b1.y,b1.z,b1.w},{b2.x,b2.y,b2.z,b2.w}};
            #pragma unroll
            for (int i = 0; i < 4; ++i)
                #pragma unroll
                for (int r = 0; r < 3; ++r)
                    #pragma unroll
                    for (int j = 0; j < 4; ++j)
                        acc[i][r][j] += a_[i] * b_[r][j];
        }
        __syncthreads();
    }

    #pragma unroll
    for (int i = 0; i < 4; ++i)
        #pragma unroll
        for (int r = 0; r < 3; ++r) {
            float4 o = make_float4(acc[i][r][0], acc[i][r][1], acc[i][r][2], acc[i][r][3]);
            *(float4*)(P + (((size_t)ks * 256 + bc0 + 4 * tb + i) * 3 + r) * 256 + n0 + 4 * tn) = o;
        }
}

// ---------------------------------------------------------------------------
// K3: reduce split-K partials (+bias) and write out = V H^T (rank 3).
// grid (2 n-tiles of 128, 256 bc), 256 threads. Coalesced 67MB stores.
// ---------------------------------------------------------------------------
__global__ __launch_bounds__(256) void k3_outer(
    const float* __restrict__ Vp, const float* __restrict__ Hp,
    const float* __restrict__ Vb, const float* __restrict__ Hb,
    float* __restrict__ out, int KSplit)
{
    __shared__ float sh[3][256];
    __shared__ float sv[3][128];

    const int bc = blockIdx.y, nt = blockIdx.x, t = threadIdx.x;

    #pragma unroll
    for (int r = 0; r < 3; ++r) {
        float a = Hb[r * 256 + t];
        for (int ks = 0; ks < KSplit; ++ks)
            a += Hp[(((size_t)ks * 256 + bc) * 3 + r) * 256 + t];
        sh[r][t] = a;
    }
    for (int idx = t; idx < 384; idx += 256) {
        int r = idx >> 7, nn = idx & 127;
        float a = Vb[r * 256 + nt * 128 + nn];
        for (int ks = 0; ks < KSplit; ++ks)
            a += Vp[(((size_t)ks * 256 + bc) * 3 + r) * 256 + nt * 128 + nn];
        sv[r][nn] = a;
    }
    __syncthreads();

    const float h0 = sh[0][t], h1 = sh[1][t], h2 = sh[2][t];
    float* ob = out + ((size_t)bc * 256 + nt * 128) * 256;
    #pragma unroll 4
    for (int nn = 0; nn < 128; ++nn)
        ob[nn * 256 + t] = sv[0][nn] * h0 + sv[1][nn] * h1 + sv[2][nn] * h2;
}

extern "C" void kernel_launch(void* const* d_in, const int* in_sizes, int n_in,
                              void* d_out, int out_size, void* d_ws, size_t ws_size,
                              hipStream_t stream)
{
    const float* x  = (const float*)d_in[0];
    const float* pe = (const float*)d_in[1];
    const float* Wv = (const float*)d_in[2];
    const float* bv = (const float*)d_in[3];
    const float* Wh = (const float*)d_in[4];
    const float* bh = (const float*)d_in[5];
    const float* Vw = (const float*)d_in[6];
    const float* Vb = (const float*)d_in[7];
    const float* Hw = (const float*)d_in[8];
    const float* Hb = (const float*)d_in[9];
    float* out = (float*)d_out;

    // ws layout (floats): [vcomp 262144][hcomp 262144][region ...]
    // region holds K1 inputs (pecol/perow/wq, 163840 fl) until K1 completes,
    // then is overlaid by the split-K partials (KS*393216 fl).
    float* ws    = (float*)d_ws;
    float* vcomp = ws;
    float* hcomp = ws + 262144;
    float* region = ws + 524288;
    float* pecol = region;                 // 65536
    float* perow = region + 65536;         // 65536
    float* wqv   = region + 131072;        // 16384
    float* wqh   = region + 147456;        // 16384

    int KS = 1;
    if      (ws_size >= (524288ull + 8*393216ull) * 4) KS = 8;
    else if (ws_size >= (524288ull + 4*393216ull) * 4) KS = 4;
    else if (ws_size >= (524288ull + 2*393216ull) * 4) KS = 2;
    const int KC = KIN / KS;

    float* Vp = region;                    // KS*196608 (overlays K1 inputs)
    float* Hp = region + (size_t)KS * 196608;

    k0_prep<<<16, 1024, 0, stream>>>(Wv, Wh, pe, (float4*)wqv, (float4*)wqh,
                                     pecol, perow);
    k1_reduce<<<256, 1024, 0, stream>>>(x, (const float4*)wqv, bv,
                                        (const float4*)wqh, bh,
                                        pecol, perow, vcomp, hcomp);
    k2_proj<<<dim3(4, 4 * KS, 2), 256, 0, stream>>>(vcomp, hcomp, Vw, Hw,
                                                    Vp, Hp, KS, KC);
    k3_outer<<<dim3(2, 256), 256, 0, stream>>>(Vp, Hp, Vb, Hb, out, KS);
}

// Round 4
// 89.453 us; speedup vs baseline: 1.5114x; 1.0512x over previous
//
#include <hip/hip_runtime.h>

#define KIN 1024

__device__ __forceinline__ float4 f4add(float4 a, float4 b) {
    return make_float4(a.x + b.x, a.y + b.y, a.z + b.z, a.w + b.w);
}
__device__ __forceinline__ float f4dot(float4 a, float4 b) {
    return a.x * b.x + a.y * b.y + a.z * b.z + a.w * b.w;
}

// ---------------------------------------------------------------------------
// K0: repack W (64 d x 256 k) -> Wq[kq][d] float4 so phase-B reads coalesce.
// ---------------------------------------------------------------------------
__global__ __launch_bounds__(256) void k0_repack(
    const float* __restrict__ Wv, const float* __restrict__ Wh,
    float4* __restrict__ Wqv, float4* __restrict__ Wqh)
{
    int idx = blockIdx.x * 256 + threadIdx.x;   // 0..4095
    int kq = idx >> 6, d = idx & 63;
    Wqv[idx] = *(const float4*)(Wv + d * 256 + 4 * kq);
    Wqh[idx] = *(const float4*)(Wh + d * 256 + 4 * kq);
}

// ---------------------------------------------------------------------------
// K1: block = (image, half of 128 rows). Images 0..255 = x[bc]; 256..271 = pe[c].
// 4 chunks of 32 rows staged HBM->LDS via global_load_lds with XOR-swizzled
// global source (linear LDS dest). colsum in registers, rowsum via transposed
// LDS reads (no shuffles). Phase B: Wq read once per block (wave = kq-eighth),
// partials combined through LDS. V output = per-half partial (summed in K2);
// H segs of a half are complete. pe blocks write pe_* buffers (folded in K2).
// ---------------------------------------------------------------------------
__global__ __launch_bounds__(1024) void k1_reduce(
    const float* __restrict__ x, const float* __restrict__ pe,
    const float4* __restrict__ Wqv, const float4* __restrict__ Wqh,
    float* __restrict__ vpart, float* __restrict__ pe_vpart,
    float* __restrict__ hcomp, float* __restrict__ pe_hcomp)
{
    __shared__ float4 stage[2048];        // 32 KB; overlaid by vpart_l in phase B
    __shared__ float colsum[16][256];     // 16 KB
    __shared__ float rowsum[128][16];     // 8 KB
    __shared__ float4 rowhalf[32][4][2];  // 4 KB
    __shared__ float hpart[8][8][64];     // 16 KB   (total 76 KB -> 2 blocks/CU)

    const int blk = blockIdx.x;
    const int h = blk & 1, bcp = blk >> 1;          // bcp 0..271
    const bool isPe = bcp >= 256;
    const int c = isPe ? (bcp - 256) : (bcp & 15);
    const float* img = isPe ? (pe + (size_t)c * 65536)
                            : (x + (size_t)bcp * 65536);
    const int t = threadIdx.x, w = t >> 6, l = t & 63;

    float4 cacc = make_float4(0.f, 0.f, 0.f, 0.f);  // colsum acc: (pr=w, colq=l)

    for (int cc = 0; cc < 4; ++cc) {
        // --- stage 32 rows: wave w stages local rows 2w, 2w+1 ---
        #pragma unroll
        for (int rr = 0; rr < 2; ++rr) {
            const int r = 2 * w + rr;               // local row, swizzle key r&7
            const int grow = h * 128 + cc * 32 + r;
            const float* src = img + (size_t)grow * 256 + 4 * (l ^ (r & 7));
            __builtin_amdgcn_global_load_lds(
                (const __attribute__((address_space(1))) unsigned int*)src,
                (__attribute__((address_space(3))) unsigned int*)&stage[r * 64],
                16, 0, 0);
        }
        __syncthreads();                             // drains vmcnt + barrier

        // --- colsum: rows w and w+16 share residue w and swizzle key ---
        {
            const int p = l ^ (w & 7);
            cacc = f4add(cacc, f4add(stage[w * 64 + p], stage[(w + 16) * 64 + p]));
        }
        // --- rowsum halves: (r, g, mh) -> 8 independent b128 reads ---
        if (t < 256) {
            const int r = t >> 3, g = (t >> 1) & 3, mh = t & 1;
            float4 s = make_float4(0.f, 0.f, 0.f, 0.f);
            #pragma unroll
            for (int i = 0; i < 8; ++i) {
                const int u = 4 * (mh * 8 + i) + g;  // logical unit: pcs 4g..4g+3
                s = f4add(s, stage[r * 64 + (u ^ (r & 7))]);
            }
            rowhalf[r][g][mh] = s;
        }
        __syncthreads();
        if (t < 128) {
            const int r = t >> 2, g = t & 3;
            *(float4*)&rowsum[cc * 32 + r][4 * g] =
                f4add(rowhalf[r][g][0], rowhalf[r][g][1]);
        }
        __syncthreads();
    }
    *(float4*)&colsum[w][4 * l] = cacc;
    __syncthreads();

    // --- phase B: wave = kq-eighth; V waves 0..7, H waves 8..15 ---
    float* vp = (float*)stage;                       // [8 kqe][16 seg][64 d]
    if (w < 8) {
        const int kq0 = w * 8;
        float acc[16];
        #pragma unroll
        for (int s = 0; s < 16; ++s) acc[s] = 0.f;
        #pragma unroll 2
        for (int kq = kq0; kq < kq0 + 8; ++kq) {
            float4 wq = Wqv[kq * 64 + l];            // coalesced, read once/block
            const int pr = kq >> 2, pc4 = (kq & 3) * 4;
            #pragma unroll
            for (int s = 0; s < 16; ++s)
                acc[s] += f4dot(wq, *(const float4*)&colsum[pr][s * 16 + pc4]);
        }
        #pragma unroll
        for (int s = 0; s < 16; ++s) vp[(w * 16 + s) * 64 + l] = acc[s];
    } else {
        const int kq0 = (w - 8) * 8;
        float acc[8];
        #pragma unroll
        for (int s = 0; s < 8; ++s) acc[s] = 0.f;
        #pragma unroll 2
        for (int kq = kq0; kq < kq0 + 8; ++kq) {
            float4 wq = Wqh[kq * 64 + l];
            const int pr = kq >> 2, pc4 = (kq & 3) * 4;
            #pragma unroll
            for (int s = 0; s < 8; ++s)
                acc[s] += f4dot(wq, *(const float4*)&rowsum[s * 16 + pr][pc4]);
        }
        #pragma unroll
        for (int s = 0; s < 8; ++s) hpart[w - 8][s][l] = acc[s];
    }
    __syncthreads();

    // --- combine + store ---
    {
        float v = 0.f;
        #pragma unroll
        for (int kqe = 0; kqe < 8; ++kqe) v += vp[kqe * 1024 + t];
        float* dst = isPe ? (pe_vpart + ((size_t)h * 16 + c) * KIN)
                          : (vpart + ((size_t)h * 256 + bcp) * KIN);
        dst[t] = v;                                  // t = seg*64+d
    }
    if (t < 512) {
        const int segl = t >> 6, d = t & 63;
        float v = 0.f;
        #pragma unroll
        for (int kqe = 0; kqe < 8; ++kqe) v += hpart[kqe][segl][d];
        float* dst = isPe ? (pe_hcomp + (size_t)c * KIN)
                          : (hcomp + (size_t)bcp * KIN);
        dst[(h * 8 + segl) * 64 + d] = v;
    }
}

// ---------------------------------------------------------------------------
// K2: P[ks][bc][r][n] = sum_k A[bc][k] * B[r][n][k], A assembled on the fly:
//   V: vpart[0]+vpart[1]+pe_vpart[0][c]+pe_vpart[1][c]+16*bv[k&63]
//   H: hcomp + pe_hcomp[c] + 16*bh[k&63]
// Tile 64bc x 64n x 3r, micro 4x3x4. grid (4 n-tiles, 4 bc-tiles * KS, 2).
// ---------------------------------------------------------------------------
__global__ __launch_bounds__(256) void k2_proj(
    const float* __restrict__ vpart, const float* __restrict__ pe_vpart,
    const float* __restrict__ hcomp, const float* __restrict__ pe_hcomp,
    const float* __restrict__ bv, const float* __restrict__ bh,
    const float* __restrict__ Vw, const float* __restrict__ Hw,
    float* __restrict__ Vp, float* __restrict__ Hp, int KSplit, int KC)
{
    __shared__ float sA[32][68];
    __shared__ float sB[32][196];

    const int mat = blockIdx.z;
    const float* B = mat ? Hw : Vw;
    float*       P = mat ? Hp : Vp;

    const int n0  = blockIdx.x * 64;
    const int bct = blockIdx.y / KSplit, ks = blockIdx.y % KSplit;
    const int bc0 = bct * 64;
    const int t   = threadIdx.x, tb = t >> 4, tn = t & 15;

    float acc[4][3][4];
    #pragma unroll
    for (int i = 0; i < 4; ++i)
        #pragma unroll
        for (int r = 0; r < 3; ++r)
            #pragma unroll
            for (int j = 0; j < 4; ++j) acc[i][r][j] = 0.f;

    const int nch = KC >> 5;
    for (int ch = 0; ch < nch; ++ch) {
        const int k0 = ks * KC + ch * 32;
        #pragma unroll
        for (int s = 0; s < 2; ++s) {               // A: 64x32, fused sum
            int q = t + s * 256;
            int bcl = q >> 3, kq = q & 7;
            int bc = bc0 + bcl, cch = bc & 15;
            size_t ko = (size_t)(k0 + 4 * kq);
            float4 bias = *(const float4*)((mat ? bh : bv) + ((k0 + 4 * kq) & 63));
            float4 v;
            if (mat == 0) {
                float4 u0 = *(const float4*)(vpart + ((size_t)0 * 256 + bc) * KIN + ko);
                float4 u1 = *(const float4*)(vpart + ((size_t)1 * 256 + bc) * KIN + ko);
                float4 w0 = *(const float4*)(pe_vpart + ((size_t)0 * 16 + cch) * KIN + ko);
                float4 w1 = *(const float4*)(pe_vpart + ((size_t)1 * 16 + cch) * KIN + ko);
                v = f4add(f4add(u0, u1), f4add(w0, w1));
            } else {
                float4 u = *(const float4*)(hcomp + (size_t)bc * KIN + ko);
                float4 p2 = *(const float4*)(pe_hcomp + (size_t)cch * KIN + ko);
                v = f4add(u, p2);
            }
            v.x += 16.f * bias.x; v.y += 16.f * bias.y;
            v.z += 16.f * bias.z; v.w += 16.f * bias.w;
            sA[4*kq+0][bcl] = v.x; sA[4*kq+1][bcl] = v.y;
            sA[4*kq+2][bcl] = v.z; sA[4*kq+3][bcl] = v.w;
        }
        #pragma unroll
        for (int s = 0; s < 6; ++s) {               // B: 192x32
            int q = t + s * 256;
            int rr = q >> 3, kq = q & 7;
            int r = rr >> 6, nn = rr & 63;
            float4 v = *(const float4*)(B + ((size_t)(r * 256 + n0 + nn)) * KIN + k0 + 4 * kq);
            sB[4*kq+0][rr] = v.x; sB[4*kq+1][rr] = v.y;
            sB[4*kq+2][rr] = v.z; sB[4*kq+3][rr] = v.w;
        }
        __syncthreads();

        #pragma unroll 8
        for (int kk = 0; kk < 32; ++kk) {
            float4 av = *(const float4*)&sA[kk][4 * tb];
            float4 b0 = *(const float4*)&sB[kk][0 * 64 + 4 * tn];
            float4 b1 = *(const float4*)&sB[kk][1 * 64 + 4 * tn];
            float4 b2 = *(const float4*)&sB[kk][2 * 64 + 4 * tn];
            float a_[4] = {av.x, av.y, av.z, av.w};
            float b_[3][4] = {{b0.x,b0.y,b0.z,b0.w},{b1.x,b1.y,b1.z,b1.w},{b2.x,b2.y,b2.z,b2.w}};
            #pragma unroll
            for (int i = 0; i < 4; ++i)
                #pragma unroll
                for (int r = 0; r < 3; ++r)
                    #pragma unroll
                    for (int j = 0; j < 4; ++j)
                        acc[i][r][j] += a_[i] * b_[r][j];
        }
        __syncthreads();
    }

    #pragma unroll
    for (int i = 0; i < 4; ++i)
        #pragma unroll
        for (int r = 0; r < 3; ++r) {
            float4 o = make_float4(acc[i][r][0], acc[i][r][1], acc[i][r][2], acc[i][r][3]);
            *(float4*)(P + (((size_t)ks * 256 + bc0 + 4 * tb + i) * 3 + r) * 256 + n0 + 4 * tn) = o;
        }
}

// ---------------------------------------------------------------------------
// K3: reduce split-K partials (+bias), out = V H^T (rank 3). Write-bound.
// ---------------------------------------------------------------------------
__global__ __launch_bounds__(256) void k3_outer(
    const float* __restrict__ Vp, const float* __restrict__ Hp,
    const float* __restrict__ Vb, const float* __restrict__ Hb,
    float* __restrict__ out, int KSplit)
{
    __shared__ float sh[3][256];
    __shared__ float sv[3][128];

    const int bc = blockIdx.y, nt = blockIdx.x, t = threadIdx.x;

    #pragma unroll
    for (int r = 0; r < 3; ++r) {
        float a = Hb[r * 256 + t];
        for (int ks = 0; ks < KSplit; ++ks)
            a += Hp[(((size_t)ks * 256 + bc) * 3 + r) * 256 + t];
        sh[r][t] = a;
    }
    for (int idx = t; idx < 384; idx += 256) {
        int r = idx >> 7, nn = idx & 127;
        float a = Vb[r * 256 + nt * 128 + nn];
        for (int ks = 0; ks < KSplit; ++ks)
            a += Vp[(((size_t)ks * 256 + bc) * 3 + r) * 256 + nt * 128 + nn];
        sv[r][nn] = a;
    }
    __syncthreads();

    const float h0 = sh[0][t], h1 = sh[1][t], h2 = sh[2][t];
    float* ob = out + ((size_t)bc * 256 + nt * 128) * 256;
    #pragma unroll 4
    for (int nn = 0; nn < 128; ++nn)
        ob[nn * 256 + t] = sv[0][nn] * h0 + sv[1][nn] * h1 + sv[2][nn] * h2;
}

extern "C" void kernel_launch(void* const* d_in, const int* in_sizes, int n_in,
                              void* d_out, int out_size, void* d_ws, size_t ws_size,
                              hipStream_t stream)
{
    const float* x  = (const float*)d_in[0];
    const float* pe = (const float*)d_in[1];
    const float* Wv = (const float*)d_in[2];
    const float* bv = (const float*)d_in[3];
    const float* Wh = (const float*)d_in[4];
    const float* bh = (const float*)d_in[5];
    const float* Vw = (const float*)d_in[6];
    const float* Vb = (const float*)d_in[7];
    const float* Hw = (const float*)d_in[8];
    const float* Hb = (const float*)d_in[9];
    float* out = (float*)d_out;

    // ws layout (floats)
    float* ws       = (float*)d_ws;
    float* vpart    = ws;                  // 2*256*1024 = 524288
    float* hcomp    = ws + 524288;         // 262144
    float* pe_vpart = ws + 786432;         // 2*16*1024 = 32768
    float* pe_hcomp = ws + 819200;         // 16384
    float* wqv      = ws + 835584;         // 16384
    float* wqh      = ws + 851968;         // 16384
    float* rest     = ws + 868352;         // split-K partials

    int KS = 1;
    if      (ws_size >= (868352ull + 8 * 393216ull) * 4) KS = 8;
    else if (ws_size >= (868352ull + 4 * 393216ull) * 4) KS = 4;
    else if (ws_size >= (868352ull + 2 * 393216ull) * 4) KS = 2;
    const int KC = KIN / KS;

    float* Vp = rest;
    float* Hp = rest + (size_t)KS * 196608;

    k0_repack<<<16, 256, 0, stream>>>(Wv, Wh, (float4*)wqv, (float4*)wqh);
    k1_reduce<<<544, 1024, 0, stream>>>(x, pe, (const float4*)wqv,
                                        (const float4*)wqh,
                                        vpart, pe_vpart, hcomp, pe_hcomp);
    k2_proj<<<dim3(4, 4 * KS, 2), 256, 0, stream>>>(
        vpart, pe_vpart, hcomp, pe_hcomp, bv, bh, Vw, Hw, Vp, Hp, KS, KC);
    k3_outer<<<dim3(2, 256), 256, 0, stream>>>(Vp, Hp, Vb, Hb, out, KS);
}

// Round 5
// 78.047 us; speedup vs baseline: 1.7323x; 1.1462x over previous
//
#include <hip/hip_runtime.h>

#define KIN 1024

__device__ __forceinline__ float4 f4add(float4 a, float4 b) {
    return make_float4(a.x + b.x, a.y + b.y, a.z + b.z, a.w + b.w);
}
__device__ __forceinline__ float f4dot(float4 a, float4 b) {
    return a.x * b.x + a.y * b.y + a.z * b.z + a.w * b.w;
}

// ---------------------------------------------------------------------------
// K1ab: fused, barrier-free, LDS-free. 272 images (0..255 = x[bc], 256..271 =
// pe[c]). Block ranges:
//   [0,16):             repack W -> Wq[kq][d] float4 (coalesced phase-B reads)
//   [16, 16+1088):      colsum: block=(img, pr-quad); wave=pr; lane=col-quad.
//                       16 independent 1KB loads, register float4 acc.
//   [1104, 1104+4352):  rowsum: block=(img, 16-row group); wave=4 rows;
//                       lane (l>>4)=row, (l&15)=unit; 4 loads + xor4/xor8.
// ---------------------------------------------------------------------------
__global__ __launch_bounds__(256) void k1ab(
    const float* __restrict__ x, const float* __restrict__ pe,
    const float* __restrict__ Wv, const float* __restrict__ Wh,
    float4* __restrict__ Wqv, float4* __restrict__ Wqh,
    float* __restrict__ colsum_buf, float* __restrict__ rowsum_buf)
{
    const int blk = blockIdx.x, t = threadIdx.x;

    if (blk < 16) {                                  // --- repack ---
        int idx = blk * 256 + t;                     // 0..4095
        int kq = idx >> 6, d = idx & 63;
        Wqv[idx] = *(const float4*)(Wv + d * 256 + 4 * kq);
        Wqh[idx] = *(const float4*)(Wh + d * 256 + 4 * kq);
        return;
    }

    const int w = t >> 6, l = t & 63;

    if (blk < 1104) {                                // --- colsum ---
        const int cb = blk - 16;                     // 0..1087
        const int img = cb >> 2;
        const int pr = (cb & 3) * 4 + w;             // 0..15
        const float* ib = (img < 256) ? (x + (size_t)img * 65536)
                                      : (pe + (size_t)(img - 256) * 65536);
        float4 v[16];
        #pragma unroll
        for (int j = 0; j < 16; ++j)
            v[j] = *(const float4*)(ib + (size_t)(pr + 16 * j) * 256 + 4 * l);
        float4 a01 = f4add(f4add(v[0], v[1]), f4add(v[2], v[3]));
        float4 a23 = f4add(f4add(v[4], v[5]), f4add(v[6], v[7]));
        float4 a45 = f4add(f4add(v[8], v[9]), f4add(v[10], v[11]));
        float4 a67 = f4add(f4add(v[12], v[13]), f4add(v[14], v[15]));
        float4 acc = f4add(f4add(a01, a23), f4add(a45, a67));
        *(float4*)(colsum_buf + (size_t)img * 4096 + pr * 256 + 4 * l) = acc;
        return;
    }

    // --- rowsum ---
    const int rb = blk - 1104;                       // 0..4351
    const int img = rb >> 4, rg = rb & 15;
    const int row = rg * 16 + w * 4 + (l >> 4);
    const int m = l & 15;
    const float* ib = (img < 256) ? (x + (size_t)img * 65536)
                                  : (pe + (size_t)(img - 256) * 65536);
    const float* rbase = ib + (size_t)row * 256;
    float4 s = make_float4(0.f, 0.f, 0.f, 0.f);
    #pragma unroll
    for (int i = 0; i < 4; ++i)
        s = f4add(s, *(const float4*)(rbase + 4 * (m + 16 * i)));
    #pragma unroll
    for (int msk = 4; msk <= 8; msk <<= 1) {
        s.x += __shfl_xor(s.x, msk);
        s.y += __shfl_xor(s.y, msk);
        s.z += __shfl_xor(s.z, msk);
        s.w += __shfl_xor(s.w, msk);
    }
    if ((l & 12) == 0)
        *(float4*)(rowsum_buf + (size_t)img * 4096 + row * 16 + 4 * (l & 3)) = s;
}

// ---------------------------------------------------------------------------
// K1c: per bc, project (colsum+pe_colsum) with Wqv and (rowsum+pe_rowsum)
// with Wqh -> vcomp/hcomp (pe + 16x bias folded). 16 waves: V waves 0..7
// own kq-eighths (all 16 segs), H waves 8..15 likewise. LDS broadcast reads.
// ---------------------------------------------------------------------------
__global__ __launch_bounds__(1024) void k1c(
    const float* __restrict__ colsum_buf, const float* __restrict__ rowsum_buf,
    const float4* __restrict__ Wqv, const float4* __restrict__ Wqh,
    const float* __restrict__ bv, const float* __restrict__ bh,
    float* __restrict__ vcomp, float* __restrict__ hcomp)
{
    __shared__ float cs[16][256];     // 16 KB
    __shared__ float rs[256][16];     // 16 KB
    __shared__ float vp[8][1024];     // 32 KB
    __shared__ float hp[8][1024];     // 32 KB  (96 KB total)

    const int bc = blockIdx.x, c = bc & 15, t = threadIdx.x;

    {
        float4 a = ((const float4*)(colsum_buf + (size_t)bc * 4096))[t];
        float4 p = ((const float4*)(colsum_buf + (size_t)(256 + c) * 4096))[t];
        ((float4*)cs)[t] = f4add(a, p);
        float4 b = ((const float4*)(rowsum_buf + (size_t)bc * 4096))[t];
        float4 q = ((const float4*)(rowsum_buf + (size_t)(256 + c) * 4096))[t];
        ((float4*)rs)[t] = f4add(b, q);
    }
    __syncthreads();

    const int w = t >> 6, l = t & 63;
    if (w < 8) {
        const int kq0 = w * 8;
        float acc[16];
        #pragma unroll
        for (int s = 0; s < 16; ++s) acc[s] = 0.f;
        #pragma unroll 2
        for (int kq = kq0; kq < kq0 + 8; ++kq) {
            float4 wq = Wqv[kq * 64 + l];            // coalesced, L2-hot
            const int pr = kq >> 2, pc4 = (kq & 3) * 4;
            #pragma unroll
            for (int s = 0; s < 16; ++s)
                acc[s] += f4dot(wq, *(const float4*)&cs[pr][s * 16 + pc4]);
        }
        #pragma unroll
        for (int s = 0; s < 16; ++s) vp[w][s * 64 + l] = acc[s];
    } else {
        const int kq0 = (w - 8) * 8;
        float acc[16];
        #pragma unroll
        for (int s = 0; s < 16; ++s) acc[s] = 0.f;
        #pragma unroll 2
        for (int kq = kq0; kq < kq0 + 8; ++kq) {
            float4 wq = Wqh[kq * 64 + l];
            const int pr = kq >> 2, pc4 = (kq & 3) * 4;
            #pragma unroll
            for (int s = 0; s < 16; ++s)
                acc[s] += f4dot(wq, *(const float4*)&rs[s * 16 + pr][pc4]);
        }
        #pragma unroll
        for (int s = 0; s < 16; ++s) hp[w - 8][s * 64 + l] = acc[s];
    }
    __syncthreads();

    {
        float v = 0.f, hsum = 0.f;
        #pragma unroll
        for (int k = 0; k < 8; ++k) { v += vp[k][t]; hsum += hp[k][t]; }
        vcomp[(size_t)bc * KIN + t] = v + 16.f * bv[t & 63];
        hcomp[(size_t)bc * KIN + t] = hsum + 16.f * bh[t & 63];
    }
}

// ---------------------------------------------------------------------------
// K2: P[ks][bc][r][n] = sum_{k in ks-chunk} A[bc][k] * B[r][n][k]
// Tile 64bc x 64n x 3r, micro 4x3x4. grid (4 n-tiles, 4 bc-tiles * KS, 2).
// ---------------------------------------------------------------------------
__global__ __launch_bounds__(256) void k2_proj(
    const float* __restrict__ vcomp, const float* __restrict__ hcomp,
    const float* __restrict__ Vw, const float* __restrict__ Hw,
    float* __restrict__ Vp, float* __restrict__ Hp, int KSplit, int KC)
{
    __shared__ float sA[32][68];
    __shared__ float sB[32][196];

    const int mat = blockIdx.z;
    const float* A = mat ? hcomp : vcomp;
    const float* B = mat ? Hw : Vw;
    float*       P = mat ? Hp : Vp;

    const int n0  = blockIdx.x * 64;
    const int bct = blockIdx.y / KSplit, ks = blockIdx.y % KSplit;
    const int bc0 = bct * 64;
    const int t   = threadIdx.x, tb = t >> 4, tn = t & 15;

    float acc[4][3][4];
    #pragma unroll
    for (int i = 0; i < 4; ++i)
        #pragma unroll
        for (int r = 0; r < 3; ++r)
            #pragma unroll
            for (int j = 0; j < 4; ++j) acc[i][r][j] = 0.f;

    const int nch = KC >> 5;
    for (int ch = 0; ch < nch; ++ch) {
        const int k0 = ks * KC + ch * 32;
        #pragma unroll
        for (int s = 0; s < 2; ++s) {               // A: 64x32
            int q = t + s * 256;
            int bcl = q >> 3, kq = q & 7;
            float4 v = *(const float4*)(A + (size_t)(bc0 + bcl) * KIN + k0 + 4 * kq);
            sA[4*kq+0][bcl] = v.x; sA[4*kq+1][bcl] = v.y;
            sA[4*kq+2][bcl] = v.z; sA[4*kq+3][bcl] = v.w;
        }
        #pragma unroll
        for (int s = 0; s < 6; ++s) {               // B: 192x32
            int q = t + s * 256;
            int rr = q >> 3, kq = q & 7;
            int r = rr >> 6, nn = rr & 63;
            float4 v = *(const float4*)(B + ((size_t)(r * 256 + n0 + nn)) * KIN + k0 + 4 * kq);
            sB[4*kq+0][rr] = v.x; sB[4*kq+1][rr] = v.y;
            sB[4*kq+2][rr] = v.z; sB[4*kq+3][rr] = v.w;
        }
        __syncthreads();

        #pragma unroll 8
        for (int kk = 0; kk < 32; ++kk) {
            float4 av = *(const float4*)&sA[kk][4 * tb];
            float4 b0 = *(const float4*)&sB[kk][0 * 64 + 4 * tn];
            float4 b1 = *(const float4*)&sB[kk][1 * 64 + 4 * tn];
            float4 b2 = *(const float4*)&sB[kk][2 * 64 + 4 * tn];
            float a_[4] = {av.x, av.y, av.z, av.w};
            float b_[3][4] = {{b0.x,b0.y,b0.z,b0.w},{b1.x,b1.y,b1.z,b1.w},{b2.x,b2.y,b2.z,b2.w}};
            #pragma unroll
            for (int i = 0; i < 4; ++i)
                #pragma unroll
                for (int r = 0; r < 3; ++r)
                    #pragma unroll
                    for (int j = 0; j < 4; ++j)
                        acc[i][r][j] += a_[i] * b_[r][j];
        }
        __syncthreads();
    }

    #pragma unroll
    for (int i = 0; i < 4; ++i)
        #pragma unroll
        for (int r = 0; r < 3; ++r) {
            float4 o = make_float4(acc[i][r][0], acc[i][r][1], acc[i][r][2], acc[i][r][3]);
            *(float4*)(P + (((size_t)ks * 256 + bc0 + 4 * tb + i) * 3 + r) * 256 + n0 + 4 * tn) = o;
        }
}

// ---------------------------------------------------------------------------
// K3: reduce split-K partials (+bias), out = V H^T (rank 3). Write-bound.
// ---------------------------------------------------------------------------
__global__ __launch_bounds__(256) void k3_outer(
    const float* __restrict__ Vp, const float* __restrict__ Hp,
    const float* __restrict__ Vb, const float* __restrict__ Hb,
    float* __restrict__ out, int KSplit)
{
    __shared__ float sh[3][256];
    __shared__ float sv[3][128];

    const int bc = blockIdx.y, nt = blockIdx.x, t = threadIdx.x;

    #pragma unroll
    for (int r = 0; r < 3; ++r) {
        float a = Hb[r * 256 + t];
        for (int ks = 0; ks < KSplit; ++ks)
            a += Hp[(((size_t)ks * 256 + bc) * 3 + r) * 256 + t];
        sh[r][t] = a;
    }
    for (int idx = t; idx < 384; idx += 256) {
        int r = idx >> 7, nn = idx & 127;
        float a = Vb[r * 256 + nt * 128 + nn];
        for (int ks = 0; ks < KSplit; ++ks)
            a += Vp[(((size_t)ks * 256 + bc) * 3 + r) * 256 + nt * 128 + nn];
        sv[r][nn] = a;
    }
    __syncthreads();

    const float h0 = sh[0][t], h1 = sh[1][t], h2 = sh[2][t];
    float* ob = out + ((size_t)bc * 256 + nt * 128) * 256;
    #pragma unroll 4
    for (int nn = 0; nn < 128; ++nn)
        ob[nn * 256 + t] = sv[0][nn] * h0 + sv[1][nn] * h1 + sv[2][nn] * h2;
}

extern "C" void kernel_launch(void* const* d_in, const int* in_sizes, int n_in,
                              void* d_out, int out_size, void* d_ws, size_t ws_size,
                              hipStream_t stream)
{
    const float* x  = (const float*)d_in[0];
    const float* pe = (const float*)d_in[1];
    const float* Wv = (const float*)d_in[2];
    const float* bv = (const float*)d_in[3];
    const float* Wh = (const float*)d_in[4];
    const float* bh = (const float*)d_in[5];
    const float* Vw = (const float*)d_in[6];
    const float* Vb = (const float*)d_in[7];
    const float* Hw = (const float*)d_in[8];
    const float* Hb = (const float*)d_in[9];
    float* out = (float*)d_out;

    // ws layout (floats)
    float* ws         = (float*)d_ws;
    float* vcomp      = ws;                    // 262144
    float* hcomp      = ws + 262144;           // 262144
    float* wqv        = ws + 524288;           // 16384
    float* wqh        = ws + 540672;           // 16384
    float* colsum_buf = ws + 557056;           // 272*4096 = 1114112
    float* rowsum_buf = ws + 1671168;          // 1114112
    float* rest       = ws + 2785280;          // split-K partials

    int KS = 1;
    if      (ws_size >= (2785280ull + 8 * 393216ull) * 4) KS = 8;
    else if (ws_size >= (2785280ull + 4 * 393216ull) * 4) KS = 4;
    else if (ws_size >= (2785280ull + 2 * 393216ull) * 4) KS = 2;
    const int KC = KIN / KS;

    float* Vp = rest;
    float* Hp = rest + (size_t)KS * 196608;

    k1ab<<<5456, 256, 0, stream>>>(x, pe, Wv, Wh, (float4*)wqv, (float4*)wqh,
                                   colsum_buf, rowsum_buf);
    k1c<<<256, 1024, 0, stream>>>(colsum_buf, rowsum_buf,
                                  (const float4*)wqv, (const float4*)wqh,
                                  bv, bh, vcomp, hcomp);
    k2_proj<<<dim3(4, 4 * KS, 2), 256, 0, stream>>>(vcomp, hcomp, Vw, Hw,
                                                    Vp, Hp, KS, KC);
    k3_outer<<<dim3(2, 256), 256, 0, stream>>>(Vp, Hp, Vb, Hb, out, KS);
}

// Round 6
// 69.637 us; speedup vs baseline: 1.9415x; 1.1208x over previous
//
#include <hip/hip_runtime.h>

#define KIN 1024

__device__ __forceinline__ float4 f4add(float4 a, float4 b) {
    return make_float4(a.x + b.x, a.y + b.y, a.z + b.z, a.w + b.w);
}
__device__ __forceinline__ float f4dot(float4 a, float4 b) {
    return a.x * b.x + a.y * b.y + a.z * b.z + a.w * b.w;
}

// ---------------------------------------------------------------------------
// K1: single-pass reduction. Block = (img, pr) over 272 images (0..255 =
// x[bc], 256..271 = pe[c]) x 16 residues. The 16 rows of residue pr ARE the
// colsum[pr] reduction set, and each row is loaded whole so its rowsum comes
// from a 4-level shfl_xor butterfly in the same pass. x/pe read ONCE (~70MB).
// Blocks [0,16) repack W -> Wq[kq][d] float4 for K1c's coalesced reads.
// 256 thr, 4KB LDS, ~20 VGPR -> 8 blocks/CU.
// ---------------------------------------------------------------------------
__global__ __launch_bounds__(256) void k1_fused(
    const float* __restrict__ x, const float* __restrict__ pe,
    const float* __restrict__ Wv, const float* __restrict__ Wh,
    float4* __restrict__ Wqv, float4* __restrict__ Wqh,
    float* __restrict__ colsum_buf, float* __restrict__ rowsum_buf)
{
    const int blk = blockIdx.x, t = threadIdx.x;

    if (blk < 16) {                                  // --- W repack ---
        int idx = blk * 256 + t;                     // 0..4095
        int kq = idx >> 6, d = idx & 63;
        Wqv[idx] = *(const float4*)(Wv + d * 256 + 4 * kq);
        Wqh[idx] = *(const float4*)(Wh + d * 256 + 4 * kq);
        return;
    }

    __shared__ float cpart[4][256];

    const int b2 = blk - 16;                         // 0..4351
    const int img = b2 >> 4, pr = b2 & 15;
    const float* ib = (img < 256) ? (x + (size_t)img * 65536)
                                  : (pe + (size_t)(img - 256) * 65536);
    const int w = t >> 6, l = t & 63;

    // wave w handles rows pr + 64w + 16j (j=0..3); lane l holds cols 4l..4l+3
    float4 v[4];
    const float* base = ib + (size_t)(pr + 64 * w) * 256 + 4 * l;
    #pragma unroll
    for (int j = 0; j < 4; ++j)
        v[j] = *(const float4*)(base + j * 4096);

    // colsum partial (register) -> LDS for cross-wave combine
    *(float4*)&cpart[w][4 * l] = f4add(f4add(v[0], v[1]), f4add(v[2], v[3]));

    // rowsum: butterfly over masks 4..32 leaves lane c (=l&3) holding
    // float4 = rowsum[row][4c..4c+3]; lanes 0..3 store 64B contiguous.
    #pragma unroll
    for (int j = 0; j < 4; ++j) {
        float4 s = v[j];
        #pragma unroll
        for (int m = 4; m <= 32; m <<= 1) {
            s.x += __shfl_xor(s.x, m);
            s.y += __shfl_xor(s.y, m);
            s.z += __shfl_xor(s.z, m);
            s.w += __shfl_xor(s.w, m);
        }
        if (l < 4) {
            const int row = pr + 64 * w + 16 * j;
            *(float4*)(rowsum_buf + (size_t)img * 4096 + row * 16 + 4 * l) = s;
        }
    }
    __syncthreads();

    colsum_buf[(size_t)img * 4096 + pr * 256 + t] =
        cpart[0][t] + cpart[1][t] + cpart[2][t] + cpart[3][t];
}

// ---------------------------------------------------------------------------
// K1c: per bc, project (colsum+pe_colsum) with Wqv and (rowsum+pe_rowsum)
// with Wqh -> vcomp/hcomp (pe + 16x bias folded). 16 waves: V waves 0..7
// own kq-eighths (all 16 segs), H waves 8..15 likewise. LDS broadcast reads.
// ---------------------------------------------------------------------------
__global__ __launch_bounds__(1024) void k1c(
    const float* __restrict__ colsum_buf, const float* __restrict__ rowsum_buf,
    const float4* __restrict__ Wqv, const float4* __restrict__ Wqh,
    const float* __restrict__ bv, const float* __restrict__ bh,
    float* __restrict__ vcomp, float* __restrict__ hcomp)
{
    __shared__ float cs[16][256];
    __shared__ float rs[256][16];
    __shared__ float vp[8][1024];
    __shared__ float hp[8][1024];

    const int bc = blockIdx.x, c = bc & 15, t = threadIdx.x;

    {
        float4 a = ((const float4*)(colsum_buf + (size_t)bc * 4096))[t];
        float4 p = ((const float4*)(colsum_buf + (size_t)(256 + c) * 4096))[t];
        ((float4*)cs)[t] = f4add(a, p);
        float4 b = ((const float4*)(rowsum_buf + (size_t)bc * 4096))[t];
        float4 q = ((const float4*)(rowsum_buf + (size_t)(256 + c) * 4096))[t];
        ((float4*)rs)[t] = f4add(b, q);
    }
    __syncthreads();

    const int w = t >> 6, l = t & 63;
    if (w < 8) {
        const int kq0 = w * 8;
        float acc[16];
        #pragma unroll
        for (int s = 0; s < 16; ++s) acc[s] = 0.f;
        #pragma unroll 2
        for (int kq = kq0; kq < kq0 + 8; ++kq) {
            float4 wq = Wqv[kq * 64 + l];
            const int pr = kq >> 2, pc4 = (kq & 3) * 4;
            #pragma unroll
            for (int s = 0; s < 16; ++s)
                acc[s] += f4dot(wq, *(const float4*)&cs[pr][s * 16 + pc4]);
        }
        #pragma unroll
        for (int s = 0; s < 16; ++s) vp[w][s * 64 + l] = acc[s];
    } else {
        const int kq0 = (w - 8) * 8;
        float acc[16];
        #pragma unroll
        for (int s = 0; s < 16; ++s) acc[s] = 0.f;
        #pragma unroll 2
        for (int kq = kq0; kq < kq0 + 8; ++kq) {
            float4 wq = Wqh[kq * 64 + l];
            const int pr = kq >> 2, pc4 = (kq & 3) * 4;
            #pragma unroll
            for (int s = 0; s < 16; ++s)
                acc[s] += f4dot(wq, *(const float4*)&rs[s * 16 + pr][pc4]);
        }
        #pragma unroll
        for (int s = 0; s < 16; ++s) hp[w - 8][s * 64 + l] = acc[s];
    }
    __syncthreads();

    {
        float v = 0.f, hsum = 0.f;
        #pragma unroll
        for (int k = 0; k < 8; ++k) { v += vp[k][t]; hsum += hp[k][t]; }
        vcomp[(size_t)bc * KIN + t] = v + 16.f * bv[t & 63];
        hcomp[(size_t)bc * KIN + t] = hsum + 16.f * bh[t & 63];
    }
}

// ---------------------------------------------------------------------------
// K2: P[ks][bc][r][n] = sum_{k in ks-chunk} A[bc][k] * B[r][n][k]
// Tile 64bc x 64n x 3r, micro 4x3x4. grid (4 n-tiles, 4 bc-tiles * KS, 2).
// ---------------------------------------------------------------------------
__global__ __launch_bounds__(256) void k2_proj(
    const float* __restrict__ vcomp, const float* __restrict__ hcomp,
    const float* __restrict__ Vw, const float* __restrict__ Hw,
    float* __restrict__ Vp, float* __restrict__ Hp, int KSplit, int KC)
{
    __shared__ float sA[32][68];
    __shared__ float sB[32][196];

    const int mat = blockIdx.z;
    const float* A = mat ? hcomp : vcomp;
    const float* B = mat ? Hw : Vw;
    float*       P = mat ? Hp : Vp;

    const int n0  = blockIdx.x * 64;
    const int bct = blockIdx.y / KSplit, ks = blockIdx.y % KSplit;
    const int bc0 = bct * 64;
    const int t   = threadIdx.x, tb = t >> 4, tn = t & 15;

    float acc[4][3][4];
    #pragma unroll
    for (int i = 0; i < 4; ++i)
        #pragma unroll
        for (int r = 0; r < 3; ++r)
            #pragma unroll
            for (int j = 0; j < 4; ++j) acc[i][r][j] = 0.f;

    const int nch = KC >> 5;
    for (int ch = 0; ch < nch; ++ch) {
        const int k0 = ks * KC + ch * 32;
        #pragma unroll
        for (int s = 0; s < 2; ++s) {               // A: 64x32
            int q = t + s * 256;
            int bcl = q >> 3, kq = q & 7;
            float4 v = *(const float4*)(A + (size_t)(bc0 + bcl) * KIN + k0 + 4 * kq);
            sA[4*kq+0][bcl] = v.x; sA[4*kq+1][bcl] = v.y;
            sA[4*kq+2][bcl] = v.z; sA[4*kq+3][bcl] = v.w;
        }
        #pragma unroll
        for (int s = 0; s < 6; ++s) {               // B: 192x32
            int q = t + s * 256;
            int rr = q >> 3, kq = q & 7;
            int r = rr >> 6, nn = rr & 63;
            float4 v = *(const float4*)(B + ((size_t)(r * 256 + n0 + nn)) * KIN + k0 + 4 * kq);
            sB[4*kq+0][rr] = v.x; sB[4*kq+1][rr] = v.y;
            sB[4*kq+2][rr] = v.z; sB[4*kq+3][rr] = v.w;
        }
        __syncthreads();

        #pragma unroll 8
        for (int kk = 0; kk < 32; ++kk) {
            float4 av = *(const float4*)&sA[kk][4 * tb];
            float4 b0 = *(const float4*)&sB[kk][0 * 64 + 4 * tn];
            float4 b1 = *(const float4*)&sB[kk][1 * 64 + 4 * tn];
            float4 b2 = *(const float4*)&sB[kk][2 * 64 + 4 * tn];
            float a_[4] = {av.x, av.y, av.z, av.w};
            float b_[3][4] = {{b0.x,b0.y,b0.z,b0.w},{b1.x,b1.y,b1.z,b1.w},{b2.x,b2.y,b2.z,b2.w}};
            #pragma unroll
            for (int i = 0; i < 4; ++i)
                #pragma unroll
                for (int r = 0; r < 3; ++r)
                    #pragma unroll
                    for (int j = 0; j < 4; ++j)
                        acc[i][r][j] += a_[i] * b_[r][j];
        }
        __syncthreads();
    }

    #pragma unroll
    for (int i = 0; i < 4; ++i)
        #pragma unroll
        for (int r = 0; r < 3; ++r) {
            float4 o = make_float4(acc[i][r][0], acc[i][r][1], acc[i][r][2], acc[i][r][3]);
            *(float4*)(P + (((size_t)ks * 256 + bc0 + 4 * tb + i) * 3 + r) * 256 + n0 + 4 * tn) = o;
        }
}

// ---------------------------------------------------------------------------
// K3: reduce split-K partials (+bias), out = V H^T (rank 3). Write-bound.
// ---------------------------------------------------------------------------
__global__ __launch_bounds__(256) void k3_outer(
    const float* __restrict__ Vp, const float* __restrict__ Hp,
    const float* __restrict__ Vb, const float* __restrict__ Hb,
    float* __restrict__ out, int KSplit)
{
    __shared__ float sh[3][256];
    __shared__ float sv[3][128];

    const int bc = blockIdx.y, nt = blockIdx.x, t = threadIdx.x;

    #pragma unroll
    for (int r = 0; r < 3; ++r) {
        float a = Hb[r * 256 + t];
        for (int ks = 0; ks < KSplit; ++ks)
            a += Hp[(((size_t)ks * 256 + bc) * 3 + r) * 256 + t];
        sh[r][t] = a;
    }
    for (int idx = t; idx < 384; idx += 256) {
        int r = idx >> 7, nn = idx & 127;
        float a = Vb[r * 256 + nt * 128 + nn];
        for (int ks = 0; ks < KSplit; ++ks)
            a += Vp[(((size_t)ks * 256 + bc) * 3 + r) * 256 + nt * 128 + nn];
        sv[r][nn] = a;
    }
    __syncthreads();

    const float h0 = sh[0][t], h1 = sh[1][t], h2 = sh[2][t];
    float* ob = out + ((size_t)bc * 256 + nt * 128) * 256;
    #pragma unroll 4
    for (int nn = 0; nn < 128; ++nn)
        ob[nn * 256 + t] = sv[0][nn] * h0 + sv[1][nn] * h1 + sv[2][nn] * h2;
}

extern "C" void kernel_launch(void* const* d_in, const int* in_sizes, int n_in,
                              void* d_out, int out_size, void* d_ws, size_t ws_size,
                              hipStream_t stream)
{
    const float* x  = (const float*)d_in[0];
    const float* pe = (const float*)d_in[1];
    const float* Wv = (const float*)d_in[2];
    const float* bv = (const float*)d_in[3];
    const float* Wh = (const float*)d_in[4];
    const float* bh = (const float*)d_in[5];
    const float* Vw = (const float*)d_in[6];
    const float* Vb = (const float*)d_in[7];
    const float* Hw = (const float*)d_in[8];
    const float* Hb = (const float*)d_in[9];
    float* out = (float*)d_out;

    // ws layout (floats)
    float* ws         = (float*)d_ws;
    float* vcomp      = ws;                    // 262144
    float* hcomp      = ws + 262144;           // 262144
    float* wqv        = ws + 524288;           // 16384
    float* wqh        = ws + 540672;           // 16384
    float* colsum_buf = ws + 557056;           // 272*4096 = 1114112
    float* rowsum_buf = ws + 1671168;          // 1114112
    float* rest       = ws + 2785280;          // split-K partials

    int KS = 1;
    if      (ws_size >= (2785280ull + 8 * 393216ull) * 4) KS = 8;
    else if (ws_size >= (2785280ull + 4 * 393216ull) * 4) KS = 4;
    else if (ws_size >= (2785280ull + 2 * 393216ull) * 4) KS = 2;
    const int KC = KIN / KS;

    float* Vp = rest;
    float* Hp = rest + (size_t)KS * 196608;

    k1_fused<<<16 + 4352, 256, 0, stream>>>(x, pe, Wv, Wh,
                                            (float4*)wqv, (float4*)wqh,
                                            colsum_buf, rowsum_buf);
    k1c<<<256, 1024, 0, stream>>>(colsum_buf, rowsum_buf,
                                  (const float4*)wqv, (const float4*)wqh,
                                  bv, bh, vcomp, hcomp);
    k2_proj<<<dim3(4, 4 * KS, 2), 256, 0, stream>>>(vcomp, hcomp, Vw, Hw,
                                                    Vp, Hp, KS, KC);
    k3_outer<<<dim3(2, 256), 256, 0, stream>>>(Vp, Hp, Vb, Hb, out, KS);
}